// Round 1
// baseline (17783.224 us; speedup 1.0000x reference)
//
#include <hip/hip_runtime.h>
#include <math.h>

#define A_TOTAL 61380
#define NGT 32
#define CICH 256

struct Ptr5 { const float* p[5]; };
struct Out5 { float* p[5]; };

// tiles per level (16x16 tiles): 1, 2, 6, 15, 60  -> cumulative 0,1,3,9,24,84
__device__ __forceinline__ void get_level(int t, int& lv, int& tile, int& H, int& W,
                                          int& tX, int& ro)
{
  if (t >= 24)      { lv = 4; tile = t - 24; H = 96; W = 160; tX = 10; ro = 15300; }
  else if (t >= 9)  { lv = 3; tile = t - 9;  H = 48; W = 80;  tX = 5;  ro = 3780;  }
  else if (t >= 3)  { lv = 2; tile = t - 3;  H = 24; W = 40;  tX = 3;  ro = 900;   }
  else if (t >= 1)  { lv = 1; tile = t - 1;  H = 12; W = 20;  tX = 2;  ro = 180;   }
  else              { lv = 0; tile = 0;      H = 6;  W = 10;  tX = 1;  ro = 0;     }
}

__device__ __forceinline__ const float* pick5(const Ptr5& s, int lv) {
  switch (lv) { case 4: return s.p[4]; case 3: return s.p[3]; case 2: return s.p[2];
                case 1: return s.p[1]; default: return s.p[0]; }
}
__device__ __forceinline__ float* pick5o(const Out5& s, int lv) {
  switch (lv) { case 4: return s.p[4]; case 3: return s.p[3]; case 2: return s.p[2];
                case 1: return s.p[1]; default: return s.p[0]; }
}

// ---------------------------------------------------------------------------
// Tower conv: 3x3, 256->256, SAME, optional ReLU. One launch covers all 5
// levels. grid = (84 tiles, 16 cout-groups, 2 batches), block = 256.
// Each block: 16x16 spatial tile x 16 cout. Input staged in LDS (4 ci at a
// time, 18x18 halo). Weights are wave-uniform -> s_load -> SGPR-operand FMA.
// ---------------------------------------------------------------------------
__global__ __launch_bounds__(256) void conv_tower(Ptr5 in, Out5 out,
    const float* __restrict__ w, const float* __restrict__ bias, int relu)
{
  int lv, tile, H, W, tX, ro;
  get_level(blockIdx.x, lv, tile, H, W, tX, ro);
  const float* xin = pick5(in, lv);
  float*       yout = pick5o(out, lv);
  const int HW = H * W;
  const int b   = blockIdx.z;
  const int cog = blockIdx.y;      // 16 groups of 16 cout
  const int tid = threadIdx.x;
  const int lx = tid & 15, ly = tid >> 4;
  const int tx0 = (tile % tX) * 16, ty0 = (tile / tX) * 16;
  const int px = tx0 + lx, py = ty0 + ly;
  const bool inb = (px < W) && (py < H);

  __shared__ float sm[4][324];     // 4 channels of 18x18 halo tile
  float acc[16];
#pragma unroll
  for (int i = 0; i < 16; ++i) acc[i] = 0.f;

  const float* xb = xin + b * CICH * HW;

  for (int c0 = 0; c0 < CICH; c0 += 4) {
    __syncthreads();
    for (int idx = tid; idx < 4 * 324; idx += 256) {
      int cc = idx / 324, r = idx - cc * 324;
      int ry = r / 18, rx = r - ry * 18;
      int yy = ty0 - 1 + ry, xx = tx0 - 1 + rx;
      float v = 0.f;
      if (yy >= 0 && yy < H && xx >= 0 && xx < W)
        v = xb[(c0 + cc) * HW + yy * W + xx];
      sm[cc][r] = v;
    }
    __syncthreads();
#pragma unroll
    for (int cc = 0; cc < 4; ++cc) {
      float v[9];
#pragma unroll
      for (int dy = 0; dy < 3; ++dy)
#pragma unroll
        for (int dx = 0; dx < 3; ++dx)
          v[dy * 3 + dx] = sm[cc][(ly + dy) * 18 + (lx + dx)];
      const int ci = c0 + cc;
      const float* wb = w + (cog * 16 * CICH + ci) * 9;
#pragma unroll
      for (int co = 0; co < 16; ++co) {
        const float* wp = wb + co * CICH * 9;
        acc[co] += wp[0]*v[0] + wp[1]*v[1] + wp[2]*v[2]
                 + wp[3]*v[3] + wp[4]*v[4] + wp[5]*v[5]
                 + wp[6]*v[6] + wp[7]*v[7] + wp[8]*v[8];
      }
    }
  }

  if (inb) {
    const int outbase = b * CICH * HW + py * W + px;
#pragma unroll
    for (int co = 0; co < 16; ++co) {
      int o = cog * 16 + co;
      float r = acc[co] + bias[o];
      if (relu) r = fmaxf(r, 0.f);
      yout[outbase + o * HW] = r;
    }
  }
}

// ---------------------------------------------------------------------------
// Fused head pair: two 3x3 convs (C1 and C2 outputs) reading the same tower
// output; writes NHWC-split layout: out[(b*A + ro + pix*3 + a)*CPA + j].
// ACT1: sigmoid on head 1. grid = (84, 2), block = 256.
// ---------------------------------------------------------------------------
template<int C1, int C2, int ACT1>
__global__ __launch_bounds__(256) void conv_heads(Ptr5 in,
    const float* __restrict__ w1, const float* __restrict__ b1, float* __restrict__ o1,
    const float* __restrict__ w2, const float* __restrict__ b2, float* __restrict__ o2)
{
  int lv, tile, H, W, tX, ro;
  get_level(blockIdx.x, lv, tile, H, W, tX, ro);
  const float* xin = pick5(in, lv);
  const int HW = H * W;
  const int b = blockIdx.y;
  const int tid = threadIdx.x;
  const int lx = tid & 15, ly = tid >> 4;
  const int tx0 = (tile % tX) * 16, ty0 = (tile / tX) * 16;
  const int px = tx0 + lx, py = ty0 + ly;
  const bool inb = (px < W) && (py < H);

  __shared__ float sm[4][324];
  float a1[C1], a2[C2];
#pragma unroll
  for (int i = 0; i < C1; ++i) a1[i] = 0.f;
#pragma unroll
  for (int i = 0; i < C2; ++i) a2[i] = 0.f;

  const float* xb = xin + b * CICH * HW;

  for (int c0 = 0; c0 < CICH; c0 += 4) {
    __syncthreads();
    for (int idx = tid; idx < 4 * 324; idx += 256) {
      int cc = idx / 324, r = idx - cc * 324;
      int ry = r / 18, rx = r - ry * 18;
      int yy = ty0 - 1 + ry, xx = tx0 - 1 + rx;
      float v = 0.f;
      if (yy >= 0 && yy < H && xx >= 0 && xx < W)
        v = xb[(c0 + cc) * HW + yy * W + xx];
      sm[cc][r] = v;
    }
    __syncthreads();
#pragma unroll
    for (int cc = 0; cc < 4; ++cc) {
      float v[9];
#pragma unroll
      for (int dy = 0; dy < 3; ++dy)
#pragma unroll
        for (int dx = 0; dx < 3; ++dx)
          v[dy * 3 + dx] = sm[cc][(ly + dy) * 18 + (lx + dx)];
      const int ci = c0 + cc;
#pragma unroll
      for (int co = 0; co < C1; ++co) {
        const float* wp = w1 + (co * CICH + ci) * 9;
        a1[co] += wp[0]*v[0] + wp[1]*v[1] + wp[2]*v[2]
                + wp[3]*v[3] + wp[4]*v[4] + wp[5]*v[5]
                + wp[6]*v[6] + wp[7]*v[7] + wp[8]*v[8];
      }
#pragma unroll
      for (int co = 0; co < C2; ++co) {
        const float* wp = w2 + (co * CICH + ci) * 9;
        a2[co] += wp[0]*v[0] + wp[1]*v[1] + wp[2]*v[2]
                + wp[3]*v[3] + wp[4]*v[4] + wp[5]*v[5]
                + wp[6]*v[6] + wp[7]*v[7] + wp[8]*v[8];
      }
    }
  }

  if (inb) {
    const int row0 = ro + (py * W + px) * 3;
    constexpr int P1 = C1 / 3, P2 = C2 / 3;
#pragma unroll
    for (int co = 0; co < C1; ++co) {
      float r = a1[co] + b1[co];
      if (ACT1) r = 1.f / (1.f + expf(-r));
      o1[(b * A_TOTAL + row0 + co / P1) * P1 + (co % P1)] = r;
    }
#pragma unroll
    for (int co = 0; co < C2; ++co) {
      float r = a2[co] + b2[co];
      o2[(b * A_TOTAL + row0 + co / P2) * P2 + (co % P2)] = r;
    }
  }
}

// ---------------------------------------------------------------------------
// Anchor generation (exact in fp32: all quantities are small integers/halves)
// ---------------------------------------------------------------------------
__global__ void gen_anchors(float* __restrict__ anchors)
{
  int i = blockIdx.x * 256 + threadIdx.x;
  if (i >= A_TOTAL) return;
  int off, s, Wl;
  if (i >= 15300)     { off = 15300; s = 8;   Wl = 160; }
  else if (i >= 3780) { off = 3780;  s = 16;  Wl = 80;  }
  else if (i >= 900)  { off = 900;   s = 32;  Wl = 40;  }
  else if (i >= 180)  { off = 180;   s = 64;  Wl = 20;  }
  else                { off = 0;     s = 128; Wl = 10;  }
  int r = i - off;
  int cell = r / 3, a = r - cell * 3;
  int y = cell / Wl, x = cell - y * Wl;
  // ratios 1,2,3 -> (ws,hs) = (4,4),(3,6),(2,6)
  float wsv = (a == 0) ? 4.f : (a == 1) ? 3.f : 2.f;
  float hsv = (a == 0) ? 4.f : 6.f;
  float sw = wsv * (float)s, sh = hsv * (float)s;
  float cx = (float)(x * s) + 1.5f, cy = (float)(y * s) + 1.5f;
  anchors[i * 4 + 0] = cx - 0.5f * (sw - 1.f);
  anchors[i * 4 + 1] = cy - 0.5f * (sh - 1.f);
  anchors[i * 4 + 2] = cx + 0.5f * (sw - 1.f);
  anchors[i * 4 + 3] = cy + 0.5f * (sh - 1.f);
}

// ---------------------------------------------------------------------------
// Anchor target: per (batch, anchor) top-2 IoU over GT, labels + bbox targets
// ---------------------------------------------------------------------------
__global__ __launch_bounds__(256) void anchor_target(
    const float* __restrict__ anchors, const float* __restrict__ gt,
    const float* __restrict__ iminfo, float* __restrict__ rpn, float* __restrict__ tgt)
{
  int i = blockIdx.x * 256 + threadIdx.x;
  int b = blockIdx.y;
  if (i >= A_TOTAL) return;
  float cnt = iminfo[b * 6 + 5];
  float ax1 = anchors[i*4+0], ay1 = anchors[i*4+1], ax2 = anchors[i*4+2], ay2 = anchors[i*4+3];
  float aw = ax2 - ax1 + 1.f, ah = ay2 - ay1 + 1.f, ab = aw * ah;
  float v1 = -1e30f, v2 = -1e30f; int i1 = 0, i2 = 0;
  for (int g = 0; g < NGT; ++g) {
    const float* gp = gt + (b * NGT + g) * 5;
    float ov = -1.f;
    if ((float)g < cnt && gp[4] != -1.f) {
      float iw = fmaxf(fminf(ax2, gp[2]) - fmaxf(ax1, gp[0]) + 1.f, 0.f);
      float ih = fmaxf(fminf(ay2, gp[3]) - fmaxf(ay1, gp[1]) + 1.f, 0.f);
      float inter = iw * ih;
      float ag = (gp[2] - gp[0] + 1.f) * (gp[3] - gp[1] + 1.f);
      ov = inter / (ab + ag - inter);
    }
    if (ov > v1)      { v2 = v1; i2 = i1; v1 = ov; i1 = g; }
    else if (ov > v2) { v2 = ov; i2 = g; }
  }
  float l1 = (v1 >= 0.5f) ? 1.f : ((v1 < 0.4f) ? 0.f : -1.f);
  float l2 = (v2 >= 0.5f) ? 1.f : ((v2 < 0.4f) ? 0.f : -1.f);
  rpn[(b * A_TOTAL + i) * 2 + 0] = l1;
  rpn[(b * A_TOTAL + i) * 2 + 1] = l2;
  float acx = ax1 + 0.5f * (aw - 1.f), acy = ay1 + 0.5f * (ah - 1.f);
  int idx2[2] = {i1, i2};
#pragma unroll
  for (int k = 0; k < 2; ++k) {
    const float* gp = gt + (b * NGT + idx2[k]) * 5;
    float gw = gp[2] - gp[0] + 1.f, gh = gp[3] - gp[1] + 1.f;
    float gcx = gp[0] + 0.5f * (gw - 1.f), gcy = gp[1] + 0.5f * (gh - 1.f);
    float* o = tgt + ((size_t)(b * 2 * A_TOTAL) + i * 2 + k) * 4;
    o[0] = (gcx - acx) / aw;  o[1] = (gcy - acy) / ah;
    o[2] = logf(gw / aw);     o[3] = logf(gh / ah);
  }
}

// ---------------------------------------------------------------------------
// IoU target: decode 2 boxes per anchor from offsets, argmax/max over GT
// ---------------------------------------------------------------------------
__global__ __launch_bounds__(256) void iou_target(
    const float* __restrict__ anchors, const float* __restrict__ gt,
    const float* __restrict__ iminfo, const float* __restrict__ offsets,
    float* __restrict__ ioust)
{
  int i = blockIdx.x * 256 + threadIdx.x;
  int b = blockIdx.y;
  if (i >= A_TOTAL) return;
  float cnt = iminfo[b * 6 + 5];
  float ax1 = anchors[i*4+0], ay1 = anchors[i*4+1], ax2 = anchors[i*4+2], ay2 = anchors[i*4+3];
  float aw = ax2 - ax1 + 1.f, ah = ay2 - ay1 + 1.f;
  float acx = ax1 + 0.5f * (aw - 1.f), acy = ay1 + 0.5f * (ah - 1.f);
  const float mx = 4.135166556742356f;  // log(1000/16)
  float bx[2][4];
#pragma unroll
  for (int k = 0; k < 2; ++k) {
    const float* d = offsets + ((size_t)(b * A_TOTAL) + i) * 8 + k * 4;
    float pw = expf(fminf(d[2], mx)) * aw;
    float ph = expf(fminf(d[3], mx)) * ah;
    float pcx = d[0] * aw + acx, pcy = d[1] * ah + acy;
    bx[k][0] = pcx - 0.5f * (pw - 1.f); bx[k][1] = pcy - 0.5f * (ph - 1.f);
    bx[k][2] = pcx + 0.5f * (pw - 1.f); bx[k][3] = pcy + 0.5f * (ph - 1.f);
  }
  float area0 = (bx[0][2]-bx[0][0]+1.f) * (bx[0][3]-bx[0][1]+1.f);
  float area1 = (bx[1][2]-bx[1][0]+1.f) * (bx[1][3]-bx[1][1]+1.f);
  float av = -1e30f; int i1 = 0;
  for (int g = 0; g < NGT; ++g) {
    const float* gp = gt + (b * NGT + g) * 5;
    float keep = ((float)g < cnt && gp[4] != -1.f) ? 1.f : 0.f;
    float ag = (gp[2] - gp[0] + 1.f) * (gp[3] - gp[1] + 1.f);
    float iw = fmaxf(fminf(bx[0][2], gp[2]) - fmaxf(bx[0][0], gp[0]) + 1.f, 0.f);
    float ih = fmaxf(fminf(bx[0][3], gp[3]) - fmaxf(bx[0][1], gp[1]) + 1.f, 0.f);
    float inter = iw * ih;
    float ov = inter / (area0 + ag - inter) * keep;
    if (ov > av) { av = ov; i1 = g; }
  }
  float bv = -1e30f;
  for (int g = 0; g < NGT; ++g) {
    float val = 0.f;
    if (g != i1) {
      const float* gp = gt + (b * NGT + g) * 5;
      float keep = ((float)g < cnt && gp[4] != -1.f) ? 1.f : 0.f;
      float ag = (gp[2] - gp[0] + 1.f) * (gp[3] - gp[1] + 1.f);
      float iw = fmaxf(fminf(bx[1][2], gp[2]) - fmaxf(bx[1][0], gp[0]) + 1.f, 0.f);
      float ih = fmaxf(fminf(bx[1][3], gp[3]) - fmaxf(bx[1][1], gp[1]) + 1.f, 0.f);
      float inter = iw * ih;
      val = inter / (area1 + ag - inter) * keep;
    }
    bv = fmaxf(bv, val);
  }
  ioust[(b * A_TOTAL + i) * 2 + 0] = av;
  ioust[(b * A_TOTAL + i) * 2 + 1] = bv;
}

// ---------------------------------------------------------------------------
// All four losses in one pass; block reduce + atomicAdd into accum[6]:
// [cls_sum, npos, bbox_sum, iou_sum, num_sum, num_cnt]
// ---------------------------------------------------------------------------
__global__ __launch_bounds__(256) void loss_reduce(
    const float* __restrict__ cls_prob, const float* __restrict__ num_prob,
    const float* __restrict__ offsets,  const float* __restrict__ iou_prob,
    const float* __restrict__ rpn,      const float* __restrict__ tgt,
    const float* __restrict__ ioust,    float* __restrict__ accum)
{
  int i = blockIdx.x * 256 + threadIdx.x;
  int b = blockIdx.y;
  float cls_s = 0.f, npos = 0.f, bb_s = 0.f, iou_s = 0.f, num_s = 0.f, num_c = 0.f;
  float la = 0.f, ign = 0.f;
  if (i < A_TOTAL) {
    int base = b * A_TOTAL + i;
    la = rpn[base * 2 + 0];
    float lb = rpn[base * 2 + 1];
    ign = lb - ((la == 0.f && lb != 0.f) ? 1.f : 0.f);
    float lab2[2] = {la, ign};
#pragma unroll
    for (int j = 0; j < 2; ++j) {
      float l = lab2[j];
      float mask = (l != -1.f) ? 1.f : 0.f;
      bool oh = (l * mask) == 1.f;
      float p = cls_prob[base * 2 + j];
      float term = oh ? (0.25f * (1.f - p) * (1.f - p) * logf(p))
                      : (0.75f * p * p * logf(1.f - p));
      cls_s += -term * mask;
      if (l > 0.f) {
        npos += 1.f;
#pragma unroll
        for (int c = 0; c < 4; ++c) {
          float d = offsets[(size_t)base * 8 + j * 4 + c]
                  - tgt[((size_t)(b * 2 * A_TOTAL) + i * 2 + j) * 4 + c];
          float ad = fabsf(d);
          bb_s += (ad < 1.f / 9.f) ? (4.5f * d * d) : (ad - 0.5f / 9.f);
        }
        iou_s += fabsf(iou_prob[base * 2 + j] - ioust[base * 2 + j]);
      }
    }
    int nl = ((la > 0.f) ? 1 : 0) + ((ign > 0.f) ? 1 : 0) - 1;
    if (nl != -1) {
      float s0 = num_prob[base * 2], s1 = num_prob[base * 2 + 1];
      float m = fmaxf(s0, s1);
      float lse = m + logf(expf(s0 - m) + expf(s1 - m));
      num_s += lse - ((nl == 0) ? s0 : s1);
      num_c += 1.f;
    }
  }
  __shared__ float red[6][4];
  float vals[6] = {cls_s, npos, bb_s, iou_s, num_s, num_c};
  int lane = threadIdx.x & 63, wid = threadIdx.x >> 6;
#pragma unroll
  for (int q = 0; q < 6; ++q) {
    float v = vals[q];
#pragma unroll
    for (int o = 32; o > 0; o >>= 1) v += __shfl_down(v, o);
    if (lane == 0) red[q][wid] = v;
  }
  __syncthreads();
  if (threadIdx.x < 6) {
    float s = red[threadIdx.x][0] + red[threadIdx.x][1] + red[threadIdx.x][2] + red[threadIdx.x][3];
    atomicAdd(&accum[threadIdx.x], s);
  }
}

__global__ void finalize_loss(const float* __restrict__ acc, float* __restrict__ out)
{
  float npos = fmaxf(acc[1], 1.f);
  out[0] = acc[0] / npos;
  out[1] = 2.f * acc[2] / npos;
  out[2] = 2.f * acc[3] / npos;
  out[3] = acc[4] / fmaxf(acc[5], 1.f);
}

// ---------------------------------------------------------------------------
extern "C" void kernel_launch(void* const* d_in, const int* in_sizes, int n_in,
                              void* d_out, int out_size, void* d_ws, size_t ws_size,
                              hipStream_t stream)
{
  (void)in_sizes; (void)n_in; (void)out_size; (void)ws_size;
  const float* feat[5];
  for (int i = 0; i < 5; ++i) feat[i] = (const float*)d_in[i];
  const float* gt      = (const float*)d_in[5];
  const float* iminfo  = (const float*)d_in[6];
  const float* cls_w   = (const float*)d_in[7];
  const float* cls_b   = (const float*)d_in[8];
  const float* box_w   = (const float*)d_in[9];
  const float* box_b   = (const float*)d_in[10];
  const float* score_w = (const float*)d_in[11];
  const float* score_b = (const float*)d_in[12];
  const float* bpred_w = (const float*)d_in[13];
  const float* bpred_b = (const float*)d_in[14];
  const float* iou_w   = (const float*)d_in[15];
  const float* iou_b   = (const float*)d_in[16];
  const float* num_w   = (const float*)d_in[17];
  const float* num_b   = (const float*)d_in[18];

  float* ws = (float*)d_ws;
  const int ACT = 2 * 256 * 20460;               // activations, all levels, n=2
  float* t0       = ws;                          // ping
  float* t1       = t0 + ACT;                    // pong
  float* cls_prob = t1 + ACT;                    // [2][A][2]
  float* num_prob = cls_prob + 2 * A_TOTAL * 2;  // [2][A][2]
  float* offsets  = num_prob + 2 * A_TOTAL * 2;  // [2][A][8]
  float* iou_prob = offsets + 2 * A_TOTAL * 8;   // [2][A][2]
  // target buffers alias onto t0 (dead after the last tower conv reads it)
  float* anchors  = t0;                          // [A][4]
  float* rpn      = anchors + A_TOTAL * 4;       // [2][A][2]
  float* tgt      = rpn + 2 * A_TOTAL * 2;       // [2][2A][4]
  float* ioust    = tgt + 2 * 2 * A_TOTAL * 4;   // [2][A][2]
  float* accum    = ioust + 2 * A_TOTAL * 2;     // [6]

  const int hw_cum[5] = {0, 60, 300, 1260, 5100};
  Ptr5 inF; Out5 oT0, oT1; Ptr5 iT0, iT1;
  for (int l = 0; l < 5; ++l) {
    inF.p[l] = feat[l];
    oT0.p[l] = t0 + 2 * 256 * hw_cum[l];
    oT1.p[l] = t1 + 2 * 256 * hw_cum[l];
    iT0.p[l] = oT0.p[l];
    iT1.p[l] = oT1.p[l];
  }

  dim3 cgrid(84, 16, 2);
  dim3 hgrid(84, 2);
  const int WL = 256 * 256 * 9;

  // cls tower -> c in t1, then score+num heads
  conv_tower<<<cgrid, 256, 0, stream>>>(inF, oT0, cls_w + 0 * WL, cls_b + 0,   1);
  conv_tower<<<cgrid, 256, 0, stream>>>(iT0, oT1, cls_w + 1 * WL, cls_b + 256, 1);
  conv_tower<<<cgrid, 256, 0, stream>>>(iT1, oT0, cls_w + 2 * WL, cls_b + 512, 1);
  conv_tower<<<cgrid, 256, 0, stream>>>(iT0, oT1, cls_w + 3 * WL, cls_b + 768, 1);
  conv_heads<6, 6, 1><<<hgrid, 256, 0, stream>>>(iT1, score_w, score_b, cls_prob,
                                                 num_w, num_b, num_prob);
  // box tower -> r in t1, then bpred+iou heads
  conv_tower<<<cgrid, 256, 0, stream>>>(inF, oT0, box_w + 0 * WL, box_b + 0,   1);
  conv_tower<<<cgrid, 256, 0, stream>>>(iT0, oT1, box_w + 1 * WL, box_b + 256, 1);
  conv_tower<<<cgrid, 256, 0, stream>>>(iT1, oT0, box_w + 2 * WL, box_b + 512, 1);
  conv_tower<<<cgrid, 256, 0, stream>>>(iT0, oT1, box_w + 3 * WL, box_b + 768, 1);
  conv_heads<24, 6, 0><<<hgrid, 256, 0, stream>>>(iT1, bpred_w, bpred_b, offsets,
                                                  iou_w, iou_b, iou_prob);

  // t0 is dead now: targets live there
  hipMemsetAsync(accum, 0, 8 * sizeof(float), stream);
  dim3 agrid((A_TOTAL + 255) / 256, 2);
  gen_anchors<<<dim3((A_TOTAL + 255) / 256), 256, 0, stream>>>(anchors);
  anchor_target<<<agrid, 256, 0, stream>>>(anchors, gt, iminfo, rpn, tgt);
  iou_target<<<agrid, 256, 0, stream>>>(anchors, gt, iminfo, offsets, ioust);
  loss_reduce<<<agrid, 256, 0, stream>>>(cls_prob, num_prob, offsets, iou_prob,
                                         rpn, tgt, ioust, accum);
  finalize_loss<<<1, 1, 0, stream>>>(accum, (float*)d_out);
}

// Round 2
// 925.016 us; speedup vs baseline: 19.2248x; 19.2248x over previous
//
#include <hip/hip_runtime.h>
#include <math.h>

#define A_TOTAL 61380
#define NGT 32

typedef _Float16 f16;
typedef f16 f16x8 __attribute__((ext_vector_type(8)));
typedef float f32x4 __attribute__((ext_vector_type(4)));

__device__ __constant__ int LV_H[5]    = {6, 12, 24, 48, 96};
__device__ __constant__ int LV_W[5]    = {10, 20, 40, 80, 160};
__device__ __constant__ int LV_BASE[5] = {0, 60, 300, 1260, 5100};
__device__ __constant__ int LV_TX[5]   = {1, 2, 3, 5, 10};   // ceil(W/16)

// ---------------------------------------------------------------------------
// Tower tile map: 4-row x 16-col tiles. tY = ceil(H/4) = {2,3,6,12,24},
// tiles per level = {2,6,18,60,240}, cum = {0,2,8,26,86,326}.
// ---------------------------------------------------------------------------
__device__ __forceinline__ void get_tile4(int t, int& lv, int& y0, int& x0)
{
  int local;
  if (t >= 86)      { lv = 4; local = t - 86; }
  else if (t >= 26) { lv = 3; local = t - 26; }
  else if (t >= 8)  { lv = 2; local = t - 8; }
  else if (t >= 2)  { lv = 1; local = t - 2; }
  else              { lv = 0; local = t; }
  int tX = LV_TX[lv];
  y0 = (local / tX) * 4;
  x0 = (local % tX) * 16;
}

// Head tile map: 16x16 tiles. tiles per level = {1,2,6,15,60}, cum {0,1,3,9,24,84}
__device__ __forceinline__ void get_tile16(int t, int& lv, int& y0, int& x0)
{
  int local;
  if (t >= 24)      { lv = 4; local = t - 24; }
  else if (t >= 9)  { lv = 3; local = t - 9; }
  else if (t >= 3)  { lv = 2; local = t - 3; }
  else if (t >= 1)  { lv = 1; local = t - 1; }
  else              { lv = 0; local = 0; }
  int tX = LV_TX[lv];
  y0 = (local / tX) * 16;
  x0 = (local % tX) * 16;
}

// ---------------------------------------------------------------------------
// NCHW fp32 feats -> NHWC f16 (LDS transpose). grid (640, 8, 2), block 256.
// ---------------------------------------------------------------------------
__global__ __launch_bounds__(256) void feats_to_nhwc(
    const float* __restrict__ f0, const float* __restrict__ f1,
    const float* __restrict__ f2, const float* __restrict__ f3,
    const float* __restrict__ f4, f16* __restrict__ act)
{
  const int b = blockIdx.z;
  const int c0 = blockIdx.y * 32;
  const int p0 = blockIdx.x * 32;
  const int tx = threadIdx.x & 31, ty = threadIdx.x >> 5;
  __shared__ float tl[32][33];

  int p = p0 + tx;
  const float* src = f0; int po = 0, HW = 60;
  if (p >= 5100)      { src = f4; po = p - 5100; HW = 15360; }
  else if (p >= 1260) { src = f3; po = p - 1260; HW = 3840; }
  else if (p >= 300)  { src = f2; po = p - 300;  HW = 960; }
  else if (p >= 60)   { src = f1; po = p - 60;   HW = 240; }
  else                { src = f0; po = p;        HW = 60; }

#pragma unroll
  for (int k = 0; k < 4; ++k) {
    int c = c0 + ty + k * 8;
    float v = 0.f;
    if (p < 20460) v = src[((size_t)b * 256 + c) * HW + po];
    tl[ty + k * 8][tx] = v;
  }
  __syncthreads();
#pragma unroll
  for (int k = 0; k < 4; ++k) {
    int pp = p0 + ty + k * 8;
    if (pp < 20460)
      act[((size_t)b * 20460 + pp) * 256 + c0 + tx] = (f16)tl[tx][ty + k * 8];
  }
}

// ---------------------------------------------------------------------------
// Tower weights fp32 [l][co][ci][3][3] -> f16 [l][co][tap][ci]
// ---------------------------------------------------------------------------
__global__ void prep_tower_w(const float* __restrict__ cls_w,
                             const float* __restrict__ box_w, f16* __restrict__ wT)
{
  int idx = blockIdx.x * 256 + threadIdx.x;   // 8*256*9*256 = 4718592
  if (idx >= 8 * 256 * 9 * 256) return;
  int ci  = idx & 255;
  int hi  = idx >> 8;               // (l*256+co)*9 + tap
  int tap = hi % 9;
  int co  = (hi / 9) & 255;
  int l   = hi / (9 * 256);
  const float* src = (l < 4) ? (cls_w + (size_t)l * 256 * 256 * 9)
                             : (box_w + (size_t)(l - 4) * 256 * 256 * 9);
  wT[idx] = (f16)src[((size_t)co * 256 + ci) * 9 + tap];
}

// Head weights -> f16 [pair][32][tap][ci] (zero-padded co) + bias hb[2][32]
__global__ void prep_head_w(const float* __restrict__ sw, const float* __restrict__ nw,
                            const float* __restrict__ bw, const float* __restrict__ iw,
                            const float* __restrict__ sb, const float* __restrict__ nb2,
                            const float* __restrict__ bb, const float* __restrict__ ib,
                            f16* __restrict__ wH, float* __restrict__ hb)
{
  int idx = blockIdx.x * 256 + threadIdx.x;   // 2*32*9*256 = 147456
  if (idx >= 2 * 32 * 9 * 256) return;
  int ci  = idx & 255;
  int hi  = idx >> 8;
  int tap = hi % 9;
  int j   = (hi / 9) & 31;
  int p   = hi / (9 * 32);
  int C1 = p ? 24 : 6;
  const float* w1 = p ? bw : sw;
  const float* w2 = p ? iw : nw;
  float v = 0.f;
  if (j < C1)          v = w1[((size_t)j * 256 + ci) * 9 + tap];
  else if (j < C1 + 6) v = w2[((size_t)(j - C1) * 256 + ci) * 9 + tap];
  wH[idx] = (f16)v;
  if (idx < 64) {
    int pp = idx >> 5, jj = idx & 31;
    int C1b = pp ? 24 : 6;
    const float* b1 = pp ? bb : sb;
    const float* b2 = pp ? ib : nb2;
    float bv = 0.f;
    if (jj < C1b)          bv = b1[jj];
    else if (jj < C1b + 6) bv = b2[jj - C1b];
    hb[idx] = bv;
  }
}

// ---------------------------------------------------------------------------
// MFMA tower conv: 3x3 256->256 + bias + ReLU, NHWC f16 in/out.
// grid (326, 2=batch), block 256 (4 waves). Tile: M=64px(4r x 16c), N=256.
// K = tap-major (9 taps x 8 ci-blocks of 32).
// ---------------------------------------------------------------------------
__global__ __launch_bounds__(256) void conv_mfma_tower(
    const f16* __restrict__ in, f16* __restrict__ out,
    const f16* __restrict__ wB, const float* __restrict__ bias)
{
  int lv, y0, x0;
  get_tile4(blockIdx.x, lv, y0, x0);
  const int H = LV_H[lv], W = LV_W[lv], base = LV_BASE[lv];
  const int b = blockIdx.y;
  const int tid = threadIdx.x;
  const int lane = tid & 63, wid = tid >> 6;
  const int m = lane & 15, q = lane >> 4;

  __shared__ __align__(16) f16 Al[6 * 18 * 40];   // [r][px][ci], px-stride 40 (32+8 pad)
  __shared__ __align__(16) f16 Bl[256 * 40];      // [co][ci], stride 40

  f32x4 acc[4][4];
#pragma unroll
  for (int i = 0; i < 4; ++i)
#pragma unroll
    for (int j = 0; j < 4; ++j) acc[i][j] = (f32x4){0.f, 0.f, 0.f, 0.f};

  const f16* inb = in + ((size_t)(b * 20460 + base)) * 256;

  for (int cb = 0; cb < 8; ++cb) {
    const int ci0 = cb * 32;
    for (int tap = 0; tap < 9; ++tap) {
      __syncthreads();
      {  // stage B: 256 co x 32 ci  (1024 units of 8 f16)
        const f16* wsrc = wB + tap * 256 + ci0;
#pragma unroll
        for (int it = 0; it < 4; ++it) {
          int u = tid + it * 256;
          int co = u >> 2, seg = u & 3;
          uint4 v = *(const uint4*)(wsrc + (size_t)co * 2304 + seg * 8);
          *(uint4*)&Bl[co * 40 + seg * 8] = v;
        }
      }
      if (tap == 0) {  // stage A: 6 rows x 18 px x 32 ci (432 units)
#pragma unroll
        for (int it = 0; it < 2; ++it) {
          int u = tid + it * 256;
          if (u < 432) {
            int r = u / 72, rem = u - r * 72;
            int px = rem >> 2, seg = rem & 3;
            int gy = y0 - 1 + r, gx = x0 - 1 + px;
            uint4 v = {0, 0, 0, 0};
            if (gy >= 0 && gy < H && gx >= 0 && gx < W)
              v = *(const uint4*)(inb + ((size_t)(gy * W + gx)) * 256 + ci0 + seg * 8);
            *(uint4*)&Al[(r * 18 + px) * 40 + seg * 8] = v;
          }
        }
      }
      __syncthreads();
      const int ky = tap / 3, kx = tap - ky * 3;
      f16x8 af[4], bf[4];
#pragma unroll
      for (int mb = 0; mb < 4; ++mb)
        af[mb] = *(const f16x8*)&Al[((mb + ky) * 18 + (m + kx)) * 40 + q * 8];
#pragma unroll
      for (int nb = 0; nb < 4; ++nb)
        bf[nb] = *(const f16x8*)&Bl[(wid * 64 + nb * 16 + m) * 40 + q * 8];
#pragma unroll
      for (int mb = 0; mb < 4; ++mb)
#pragma unroll
        for (int nb = 0; nb < 4; ++nb)
          acc[mb][nb] = __builtin_amdgcn_mfma_f32_16x16x32_f16(af[mb], bf[nb], acc[mb][nb], 0, 0, 0);
    }
  }

  // epilogue: D row(=x offset)=q*4+reg, col(=co)=lane&15
#pragma unroll
  for (int mb = 0; mb < 4; ++mb) {
    int y = y0 + mb;
    if (y >= H) continue;
#pragma unroll
    for (int nb = 0; nb < 4; ++nb) {
      int co = wid * 64 + nb * 16 + m;
      float bi = bias[co];
#pragma unroll
      for (int r = 0; r < 4; ++r) {
        int x = x0 + q * 4 + r;
        if (x < W) {
          float v = fmaxf(acc[mb][nb][r] + bi, 0.f);
          out[((size_t)(b * 20460 + base + y * W + x)) * 256 + co] = (f16)v;
        }
      }
    }
  }
}

// ---------------------------------------------------------------------------
// MFMA head conv pair: N=32 (C1+C2 real, rest pad). Tile M=256px (16x16),
// each wave does 4 rows. Epilogue writes round-1 layouts (+sigmoid for o1).
// grid (84, 2=batch), block 256.
// ---------------------------------------------------------------------------
template <int C1, int C2, int SIG>
__global__ __launch_bounds__(256) void conv_mfma_head(
    const f16* __restrict__ in, const f16* __restrict__ wB,
    const float* __restrict__ hb, float* __restrict__ o1, float* __restrict__ o2)
{
  int lv, y0, x0;
  get_tile16(blockIdx.x, lv, y0, x0);
  const int H = LV_H[lv], W = LV_W[lv], base = LV_BASE[lv];
  const int b = blockIdx.y;
  const int tid = threadIdx.x;
  const int lane = tid & 63, wid = tid >> 6;
  const int m = lane & 15, q = lane >> 4;

  __shared__ __align__(16) f16 Al[18 * 18 * 40];  // [r][px][ci]
  __shared__ __align__(16) f16 Bl[32 * 40];

  f32x4 acc[4][2];
#pragma unroll
  for (int i = 0; i < 4; ++i) { acc[i][0] = (f32x4){0,0,0,0}; acc[i][1] = (f32x4){0,0,0,0}; }

  const f16* inb = in + ((size_t)(b * 20460 + base)) * 256;

  for (int cb = 0; cb < 8; ++cb) {
    const int ci0 = cb * 32;
    for (int tap = 0; tap < 9; ++tap) {
      __syncthreads();
      if (tid < 128) {  // stage B: 32 co x 32 ci (128 units)
        int co = tid >> 2, seg = tid & 3;
        uint4 v = *(const uint4*)(wB + (size_t)co * 2304 + tap * 256 + ci0 + seg * 8);
        *(uint4*)&Bl[co * 40 + seg * 8] = v;
      }
      if (tap == 0) {  // stage A: 18 rows x 18 px x 32 ci (1296 units)
#pragma unroll
        for (int it = 0; it < 6; ++it) {
          int u = tid + it * 256;
          if (u < 1296) {
            int r = u / 72, rem = u - r * 72;
            int px = rem >> 2, seg = rem & 3;
            int gy = y0 - 1 + r, gx = x0 - 1 + px;
            uint4 v = {0, 0, 0, 0};
            if (gy >= 0 && gy < H && gx >= 0 && gx < W)
              v = *(const uint4*)(inb + ((size_t)(gy * W + gx)) * 256 + ci0 + seg * 8);
            *(uint4*)&Al[(r * 18 + px) * 40 + seg * 8] = v;
          }
        }
      }
      __syncthreads();
      const int ky = tap / 3, kx = tap - ky * 3;
      f16x8 af[4], bf[2];
#pragma unroll
      for (int mb = 0; mb < 4; ++mb)
        af[mb] = *(const f16x8*)&Al[((wid * 4 + mb + ky) * 18 + (m + kx)) * 40 + q * 8];
#pragma unroll
      for (int nb = 0; nb < 2; ++nb)
        bf[nb] = *(const f16x8*)&Bl[(nb * 16 + m) * 40 + q * 8];
#pragma unroll
      for (int mb = 0; mb < 4; ++mb)
#pragma unroll
        for (int nb = 0; nb < 2; ++nb)
          acc[mb][nb] = __builtin_amdgcn_mfma_f32_16x16x32_f16(af[mb], bf[nb], acc[mb][nb], 0, 0, 0);
    }
  }

  constexpr int P1 = C1 / 3, P2 = C2 / 3;
  const int ro = base * 3;
#pragma unroll
  for (int mb = 0; mb < 4; ++mb) {
    int y = y0 + wid * 4 + mb;
    if (y >= H) continue;
#pragma unroll
    for (int nb = 0; nb < 2; ++nb) {
      int j = nb * 16 + m;
      if (j >= C1 + C2) continue;
      float bi = hb[j];
#pragma unroll
      for (int r = 0; r < 4; ++r) {
        int x = x0 + q * 4 + r;
        if (x < W) {
          float v = acc[mb][nb][r] + bi;
          int row0 = ro + (y * W + x) * 3;
          if (j < C1) {
            if (SIG) v = 1.f / (1.f + expf(-v));
            o1[((size_t)b * A_TOTAL + row0 + j / P1) * P1 + (j % P1)] = v;
          } else {
            int jj = j - C1;
            o2[((size_t)b * A_TOTAL + row0 + jj / P2) * P2 + (jj % P2)] = v;
          }
        }
      }
    }
  }
}

// ---------------------------------------------------------------------------
// Anchor generation (exact in fp32)
// ---------------------------------------------------------------------------
__global__ void gen_anchors(float* __restrict__ anchors)
{
  int i = blockIdx.x * 256 + threadIdx.x;
  if (i >= A_TOTAL) return;
  int off, s, Wl;
  if (i >= 15300)     { off = 15300; s = 8;   Wl = 160; }
  else if (i >= 3780) { off = 3780;  s = 16;  Wl = 80;  }
  else if (i >= 900)  { off = 900;   s = 32;  Wl = 40;  }
  else if (i >= 180)  { off = 180;   s = 64;  Wl = 20;  }
  else                { off = 0;     s = 128; Wl = 10;  }
  int r = i - off;
  int cell = r / 3, a = r - cell * 3;
  int y = cell / Wl, x = cell - y * Wl;
  float wsv = (a == 0) ? 4.f : (a == 1) ? 3.f : 2.f;
  float hsv = (a == 0) ? 4.f : 6.f;
  float sw = wsv * (float)s, sh = hsv * (float)s;
  float cx = (float)(x * s) + 1.5f, cy = (float)(y * s) + 1.5f;
  anchors[i * 4 + 0] = cx - 0.5f * (sw - 1.f);
  anchors[i * 4 + 1] = cy - 0.5f * (sh - 1.f);
  anchors[i * 4 + 2] = cx + 0.5f * (sw - 1.f);
  anchors[i * 4 + 3] = cy + 0.5f * (sh - 1.f);
}

__global__ __launch_bounds__(256) void anchor_target(
    const float* __restrict__ anchors, const float* __restrict__ gt,
    const float* __restrict__ iminfo, float* __restrict__ rpn, float* __restrict__ tgt)
{
  int i = blockIdx.x * 256 + threadIdx.x;
  int b = blockIdx.y;
  if (i >= A_TOTAL) return;
  float cnt = iminfo[b * 6 + 5];
  float ax1 = anchors[i*4+0], ay1 = anchors[i*4+1], ax2 = anchors[i*4+2], ay2 = anchors[i*4+3];
  float aw = ax2 - ax1 + 1.f, ah = ay2 - ay1 + 1.f, ab = aw * ah;
  float v1 = -1e30f, v2 = -1e30f; int i1 = 0, i2 = 0;
  for (int g = 0; g < NGT; ++g) {
    const float* gp = gt + (b * NGT + g) * 5;
    float ov = -1.f;
    if ((float)g < cnt && gp[4] != -1.f) {
      float iw = fmaxf(fminf(ax2, gp[2]) - fmaxf(ax1, gp[0]) + 1.f, 0.f);
      float ih = fmaxf(fminf(ay2, gp[3]) - fmaxf(ay1, gp[1]) + 1.f, 0.f);
      float inter = iw * ih;
      float ag = (gp[2] - gp[0] + 1.f) * (gp[3] - gp[1] + 1.f);
      ov = inter / (ab + ag - inter);
    }
    if (ov > v1)      { v2 = v1; i2 = i1; v1 = ov; i1 = g; }
    else if (ov > v2) { v2 = ov; i2 = g; }
  }
  float l1 = (v1 >= 0.5f) ? 1.f : ((v1 < 0.4f) ? 0.f : -1.f);
  float l2 = (v2 >= 0.5f) ? 1.f : ((v2 < 0.4f) ? 0.f : -1.f);
  rpn[(b * A_TOTAL + i) * 2 + 0] = l1;
  rpn[(b * A_TOTAL + i) * 2 + 1] = l2;
  float acx = ax1 + 0.5f * (aw - 1.f), acy = ay1 + 0.5f * (ah - 1.f);
  int idx2[2] = {i1, i2};
#pragma unroll
  for (int k = 0; k < 2; ++k) {
    const float* gp = gt + (b * NGT + idx2[k]) * 5;
    float gw = gp[2] - gp[0] + 1.f, gh = gp[3] - gp[1] + 1.f;
    float gcx = gp[0] + 0.5f * (gw - 1.f), gcy = gp[1] + 0.5f * (gh - 1.f);
    float* o = tgt + ((size_t)(b * 2 * A_TOTAL) + i * 2 + k) * 4;
    o[0] = (gcx - acx) / aw;  o[1] = (gcy - acy) / ah;
    o[2] = logf(gw / aw);     o[3] = logf(gh / ah);
  }
}

__global__ __launch_bounds__(256) void iou_target(
    const float* __restrict__ anchors, const float* __restrict__ gt,
    const float* __restrict__ iminfo, const float* __restrict__ offsets,
    float* __restrict__ ioust)
{
  int i = blockIdx.x * 256 + threadIdx.x;
  int b = blockIdx.y;
  if (i >= A_TOTAL) return;
  float cnt = iminfo[b * 6 + 5];
  float ax1 = anchors[i*4+0], ay1 = anchors[i*4+1], ax2 = anchors[i*4+2], ay2 = anchors[i*4+3];
  float aw = ax2 - ax1 + 1.f, ah = ay2 - ay1 + 1.f;
  float acx = ax1 + 0.5f * (aw - 1.f), acy = ay1 + 0.5f * (ah - 1.f);
  const float mx = 4.135166556742356f;
  float bx[2][4];
#pragma unroll
  for (int k = 0; k < 2; ++k) {
    const float* d = offsets + ((size_t)(b * A_TOTAL) + i) * 8 + k * 4;
    float pw = expf(fminf(d[2], mx)) * aw;
    float ph = expf(fminf(d[3], mx)) * ah;
    float pcx = d[0] * aw + acx, pcy = d[1] * ah + acy;
    bx[k][0] = pcx - 0.5f * (pw - 1.f); bx[k][1] = pcy - 0.5f * (ph - 1.f);
    bx[k][2] = pcx + 0.5f * (pw - 1.f); bx[k][3] = pcy + 0.5f * (ph - 1.f);
  }
  float area0 = (bx[0][2]-bx[0][0]+1.f) * (bx[0][3]-bx[0][1]+1.f);
  float area1 = (bx[1][2]-bx[1][0]+1.f) * (bx[1][3]-bx[1][1]+1.f);
  float av = -1e30f; int i1 = 0;
  for (int g = 0; g < NGT; ++g) {
    const float* gp = gt + (b * NGT + g) * 5;
    float keep = ((float)g < cnt && gp[4] != -1.f) ? 1.f : 0.f;
    float ag = (gp[2] - gp[0] + 1.f) * (gp[3] - gp[1] + 1.f);
    float iw = fmaxf(fminf(bx[0][2], gp[2]) - fmaxf(bx[0][0], gp[0]) + 1.f, 0.f);
    float ih = fmaxf(fminf(bx[0][3], gp[3]) - fmaxf(bx[0][1], gp[1]) + 1.f, 0.f);
    float inter = iw * ih;
    float ov = inter / (area0 + ag - inter) * keep;
    if (ov > av) { av = ov; i1 = g; }
  }
  float bv = -1e30f;
  for (int g = 0; g < NGT; ++g) {
    float val = 0.f;
    if (g != i1) {
      const float* gp = gt + (b * NGT + g) * 5;
      float keep = ((float)g < cnt && gp[4] != -1.f) ? 1.f : 0.f;
      float ag = (gp[2] - gp[0] + 1.f) * (gp[3] - gp[1] + 1.f);
      float iw = fmaxf(fminf(bx[1][2], gp[2]) - fmaxf(bx[1][0], gp[0]) + 1.f, 0.f);
      float ih = fmaxf(fminf(bx[1][3], gp[3]) - fmaxf(bx[1][1], gp[1]) + 1.f, 0.f);
      float inter = iw * ih;
      val = inter / (area1 + ag - inter) * keep;
    }
    bv = fmaxf(bv, val);
  }
  ioust[(b * A_TOTAL + i) * 2 + 0] = av;
  ioust[(b * A_TOTAL + i) * 2 + 1] = bv;
}

__global__ __launch_bounds__(256) void loss_reduce(
    const float* __restrict__ cls_prob, const float* __restrict__ num_prob,
    const float* __restrict__ offsets,  const float* __restrict__ iou_prob,
    const float* __restrict__ rpn,      const float* __restrict__ tgt,
    const float* __restrict__ ioust,    float* __restrict__ accum)
{
  int i = blockIdx.x * 256 + threadIdx.x;
  int b = blockIdx.y;
  float cls_s = 0.f, npos = 0.f, bb_s = 0.f, iou_s = 0.f, num_s = 0.f, num_c = 0.f;
  float la = 0.f, ign = 0.f;
  if (i < A_TOTAL) {
    int base = b * A_TOTAL + i;
    la = rpn[base * 2 + 0];
    float lb = rpn[base * 2 + 1];
    ign = lb - ((la == 0.f && lb != 0.f) ? 1.f : 0.f);
    float lab2[2] = {la, ign};
#pragma unroll
    for (int j = 0; j < 2; ++j) {
      float l = lab2[j];
      float mask = (l != -1.f) ? 1.f : 0.f;
      bool oh = (l * mask) == 1.f;
      float p = cls_prob[base * 2 + j];
      float term = oh ? (0.25f * (1.f - p) * (1.f - p) * logf(p))
                      : (0.75f * p * p * logf(1.f - p));
      cls_s += -term * mask;
      if (l > 0.f) {
        npos += 1.f;
#pragma unroll
        for (int c = 0; c < 4; ++c) {
          float d = offsets[(size_t)base * 8 + j * 4 + c]
                  - tgt[((size_t)(b * 2 * A_TOTAL) + i * 2 + j) * 4 + c];
          float ad = fabsf(d);
          bb_s += (ad < 1.f / 9.f) ? (4.5f * d * d) : (ad - 0.5f / 9.f);
        }
        iou_s += fabsf(iou_prob[base * 2 + j] - ioust[base * 2 + j]);
      }
    }
    int nl = ((la > 0.f) ? 1 : 0) + ((ign > 0.f) ? 1 : 0) - 1;
    if (nl != -1) {
      float s0 = num_prob[base * 2], s1 = num_prob[base * 2 + 1];
      float mm = fmaxf(s0, s1);
      float lse = mm + logf(expf(s0 - mm) + expf(s1 - mm));
      num_s += lse - ((nl == 0) ? s0 : s1);
      num_c += 1.f;
    }
  }
  __shared__ float red[6][4];
  float vals[6] = {cls_s, npos, bb_s, iou_s, num_s, num_c};
  int lane = threadIdx.x & 63, wid = threadIdx.x >> 6;
#pragma unroll
  for (int qq = 0; qq < 6; ++qq) {
    float v = vals[qq];
#pragma unroll
    for (int o = 32; o > 0; o >>= 1) v += __shfl_down(v, o);
    if (lane == 0) red[qq][wid] = v;
  }
  __syncthreads();
  if (threadIdx.x < 6) {
    float s = red[threadIdx.x][0] + red[threadIdx.x][1] + red[threadIdx.x][2] + red[threadIdx.x][3];
    atomicAdd(&accum[threadIdx.x], s);
  }
}

__global__ void finalize_loss(const float* __restrict__ acc, float* __restrict__ out)
{
  float npos = fmaxf(acc[1], 1.f);
  out[0] = acc[0] / npos;
  out[1] = 2.f * acc[2] / npos;
  out[2] = 2.f * acc[3] / npos;
  out[3] = acc[4] / fmaxf(acc[5], 1.f);
}

// ---------------------------------------------------------------------------
extern "C" void kernel_launch(void* const* d_in, const int* in_sizes, int n_in,
                              void* d_out, int out_size, void* d_ws, size_t ws_size,
                              hipStream_t stream)
{
  (void)in_sizes; (void)n_in; (void)out_size; (void)ws_size;
  const float* feat[5];
  for (int i = 0; i < 5; ++i) feat[i] = (const float*)d_in[i];
  const float* gt      = (const float*)d_in[5];
  const float* iminfo  = (const float*)d_in[6];
  const float* cls_w   = (const float*)d_in[7];
  const float* cls_b   = (const float*)d_in[8];
  const float* box_w   = (const float*)d_in[9];
  const float* box_b   = (const float*)d_in[10];
  const float* score_w = (const float*)d_in[11];
  const float* score_b = (const float*)d_in[12];
  const float* bpred_w = (const float*)d_in[13];
  const float* bpred_b = (const float*)d_in[14];
  const float* iou_w   = (const float*)d_in[15];
  const float* iou_b   = (const float*)d_in[16];
  const float* num_w   = (const float*)d_in[17];
  const float* num_b   = (const float*)d_in[18];

  const size_t ACT = (size_t)2 * 20460 * 256;      // 10,475,520 f16
  f16* actF = (f16*)d_ws;
  f16* actA = actF + ACT;
  f16* actB = actA + ACT;
  f16* wT   = actB + ACT;                          // 8*256*9*256
  f16* wH   = wT + (size_t)8 * 256 * 9 * 256;      // 2*32*9*256
  float* hb = (float*)(wH + (size_t)2 * 32 * 9 * 256);
  float* cls_prob = hb + 64;                       // 2*A*2
  float* num_prob = cls_prob + 2 * A_TOTAL * 2;
  float* offsets  = num_prob + 2 * A_TOTAL * 2;    // 2*A*8
  float* iou_prob = offsets + 2 * A_TOTAL * 8;
  float* anchors  = iou_prob + 2 * A_TOTAL * 2;    // A*4
  float* rpn      = anchors + A_TOTAL * 4;         // 2*A*2
  float* tgt      = rpn + 2 * A_TOTAL * 2;         // 2*2A*4
  float* ioust    = tgt + 2 * 2 * A_TOTAL * 4;     // 2*A*2
  float* accum    = ioust + 2 * A_TOTAL * 2;       // 8

  prep_tower_w<<<dim3((8*256*9*256) / 256), 256, 0, stream>>>(cls_w, box_w, wT);
  prep_head_w<<<dim3((2*32*9*256) / 256), 256, 0, stream>>>(
      score_w, num_w, bpred_w, iou_w, score_b, num_b, bpred_b, iou_b, wH, hb);
  feats_to_nhwc<<<dim3(640, 8, 2), 256, 0, stream>>>(
      feat[0], feat[1], feat[2], feat[3], feat[4], actF);

  const size_t WT = (size_t)256 * 9 * 256;
  dim3 tg(326, 2), hg(84, 2);
  // cls tower
  conv_mfma_tower<<<tg, 256, 0, stream>>>(actF, actA, wT + 0 * WT, cls_b + 0);
  conv_mfma_tower<<<tg, 256, 0, stream>>>(actA, actB, wT + 1 * WT, cls_b + 256);
  conv_mfma_tower<<<tg, 256, 0, stream>>>(actB, actA, wT + 2 * WT, cls_b + 512);
  conv_mfma_tower<<<tg, 256, 0, stream>>>(actA, actB, wT + 3 * WT, cls_b + 768);
  conv_mfma_head<6, 6, 1><<<hg, 256, 0, stream>>>(actB, wH, hb, cls_prob, num_prob);
  // box tower
  conv_mfma_tower<<<tg, 256, 0, stream>>>(actF, actA, wT + 4 * WT, box_b + 0);
  conv_mfma_tower<<<tg, 256, 0, stream>>>(actA, actB, wT + 5 * WT, box_b + 256);
  conv_mfma_tower<<<tg, 256, 0, stream>>>(actB, actA, wT + 6 * WT, box_b + 512);
  conv_mfma_tower<<<tg, 256, 0, stream>>>(actA, actB, wT + 7 * WT, box_b + 768);
  conv_mfma_head<24, 6, 0><<<hg, 256, 0, stream>>>(actB, wH + (size_t)32 * 9 * 256,
                                                   hb + 32, offsets, iou_prob);

  hipMemsetAsync(accum, 0, 8 * sizeof(float), stream);
  dim3 agrid((A_TOTAL + 255) / 256, 2);
  gen_anchors<<<dim3((A_TOTAL + 255) / 256), 256, 0, stream>>>(anchors);
  anchor_target<<<agrid, 256, 0, stream>>>(anchors, gt, iminfo, rpn, tgt);
  iou_target<<<agrid, 256, 0, stream>>>(anchors, gt, iminfo, offsets, ioust);
  loss_reduce<<<agrid, 256, 0, stream>>>(cls_prob, num_prob, offsets, iou_prob,
                                         rpn, tgt, ioust, accum);
  finalize_loss<<<1, 1, 0, stream>>>(accum, (float*)d_out);
}